// Round 6
// baseline (62.176 us; speedup 1.0000x reference)
//
#include <hip/hip_runtime.h>

typedef __attribute__((ext_vector_type(8))) short short8;
typedef __attribute__((ext_vector_type(4))) float f32x4;

#define B_DIM 2048
#define P_DIM 2048
#define R_DIM 4096
#define H_DIM 6
#define M_DIM 256
#define A_DIM 256
#define OUT_STRIDE 2560   // P + M + A
#define NB 2              // batch rows per main_fused block
#define VSTRIDE 2064      // vrow row stride (sentinel at 2048; +16 bank offset)

// exp2-form constants: y = -C1*val;  g = -K2*(ymax+log2 s)*gate
#define C1 14.426950408889634f   // 10/ln2
#define K2 0.06931471805599453f  // ln2/10
#define C2 7.213475204444817f    // 5/ln2
#define K3 0.13862943611198906f  // ln2/5

static __device__ __forceinline__ unsigned short f2bf(float f) {
    unsigned u = __builtin_bit_cast(unsigned, f);
    u += 0x7fffu + ((u >> 16) & 1u);          // round-to-nearest-even
    return (unsigned short)(u >> 16);
}

// ---------------------------------------------------------------------------
// prep_all: one launch, block-range branching.
//   bid <  2048 : transpose+scale GA/GB -> GAT/GBT (bf16, N x K)
//   2048..2303  : cast w -> bf16
//   2304..2319  : pack rule metadata (6x u16 idx, masked -> 2048; u16 head)
// ---------------------------------------------------------------------------
__global__ __launch_bounds__(256) void prep_all(
    const float* __restrict__ GA, const float* __restrict__ GB,
    const float* __restrict__ isM, const float* __restrict__ isA,
    const float* __restrict__ w,
    const int* __restrict__ bidx, const float* __restrict__ bmask,
    const int* __restrict__ hidx,
    unsigned short* __restrict__ GAT, unsigned short* __restrict__ GBT,
    unsigned short* __restrict__ wb, uint4* __restrict__ meta)
{
    __shared__ float t[32][33];
    const int bid = blockIdx.x;
    if (bid < 2048) {
        const int which = bid >> 10;
        const int rem = bid & 1023;
        const float* src = which ? GB : GA;
        const float* scv = which ? isA : isM;
        unsigned short* dst = which ? GBT : GAT;
        const int r0 = (rem >> 3) * 32;   // K (=R) dim
        const int n0 = (rem & 7) * 32;    // N (=256) dim
        const int tx = threadIdx.x & 31, ty = threadIdx.x >> 5;
        #pragma unroll
        for (int q = 0; q < 4; q++) {
            int rr = ty + q * 8;
            t[rr][tx] = scv[r0 + rr] * src[(size_t)(r0 + rr) * 256 + n0 + tx];
        }
        __syncthreads();
        #pragma unroll
        for (int q = 0; q < 4; q++) {
            int nn = ty + q * 8;
            dst[(size_t)(n0 + nn) * R_DIM + r0 + tx] = f2bf(t[tx][nn]);
        }
    } else if (bid < 2304) {
        const int i = (bid - 2048) * 256 + threadIdx.x;   // 65536
        wb[i] = f2bf(w[i]);
    } else {
        const int r = (bid - 2304) * 256 + threadIdx.x;   // 4096
        const int* bi = bidx + r * H_DIM;
        const float* bm = bmask + r * H_DIM;
        unsigned s[H_DIM];
        #pragma unroll
        for (int h = 0; h < H_DIM; h++)
            s[h] = (bm[h] > 0.0f) ? (unsigned)bi[h] : 2048u;
        const int hh = hidx[r];
        unsigned sh = (hh < M_DIM) ? (unsigned)hh : 0xFFFFu;
        uint4 m;
        m.x = s[0] | (s[1] << 16);
        m.y = s[2] | (s[3] << 16);
        m.z = s[4] | (s[5] << 16);
        m.w = sh;
        meta[r] = m;
    }
}

// ---------------------------------------------------------------------------
// Main fused kernel: NB=2 rows/block, 512 threads, grid 1024.
// vrow stored as y = -C1*val so soft-min = max + exp2 (1 sub + 1 trans/term).
// ---------------------------------------------------------------------------
__global__ __launch_bounds__(512, 8) void main_fused(
    const float* __restrict__ M_minus, const float* __restrict__ amask,
    const float* __restrict__ gate,    const uint4* __restrict__ meta,
    unsigned short* __restrict__ g_bf, unsigned short* __restrict__ mclip_bf,
    float* __restrict__ outp)
{
    __shared__ float vrow[NB][VSTRIDE];
    __shared__ float shead[NB][M_DIM];
    const int b0 = blockIdx.x * NB;
    const int tid = threadIdx.x;

    if (tid < M_DIM) {
        shead[0][tid] = 0.0f;
        shead[1][tid] = 0.0f;
    }
    if (tid < NB) vrow[tid][2048] = -1.0e9f;   // sentinel (masked bodies)

    // phase 1: build NB val rows in y-form (one float4 per thread per row)
    #pragma unroll
    for (int r = 0; r < NB; r++) {
        const int c = tid;
        float4 v = ((const float4*)(amask + (size_t)(b0 + r) * P_DIM))[c];
        if (c < M_DIM / 4) {
            float4 m = ((const float4*)(M_minus + (size_t)(b0 + r) * M_DIM))[c];
            float mc0 = fminf(fmaxf(m.x, 0.0f), 1.0f);
            float mc1 = fminf(fmaxf(m.y, 0.0f), 1.0f);
            float mc2 = fminf(fmaxf(m.z, 0.0f), 1.0f);
            float mc3 = fminf(fmaxf(m.w, 0.0f), 1.0f);
            ushort4 mb; mb.x = f2bf(mc0); mb.y = f2bf(mc1); mb.z = f2bf(mc2); mb.w = f2bf(mc3);
            ((ushort4*)(mclip_bf + (size_t)(b0 + r) * M_DIM))[c] = mb;
            v.x = fmaxf(mc0, v.x); v.y = fmaxf(mc1, v.y);
            v.z = fmaxf(mc2, v.z); v.w = fmaxf(mc3, v.w);
        }
        float4 y;
        y.x = -C1 * v.x; y.y = -C1 * v.y; y.z = -C1 * v.z; y.w = -C1 * v.w;
        ((float4*)vrow[r])[c] = y;
    }
    __syncthreads();

    // phase 2: rules, 8 iterations, prefetch distance 1
    const float* g0p = gate + (size_t)b0 * R_DIM;
    const float* g1p = gate + (size_t)(b0 + 1) * R_DIM;
    unsigned short* o0p = g_bf + (size_t)b0 * R_DIM;
    unsigned short* o1p = g_bf + (size_t)(b0 + 1) * R_DIM;

    uint4 mc = meta[tid];
    float ga = g0p[tid], gb = g1p[tid];
    #pragma unroll 2
    for (int it = 0; it < R_DIM / 512; it++) {
        const int rr = tid + it * 512;
        uint4 mn = mc; float gan = ga, gbn = gb;
        if (it < R_DIM / 512 - 1) {
            mn  = meta[rr + 512];
            gan = g0p[rr + 512];
            gbn = g1p[rr + 512];
        }
        const int i0 = mc.x & 0xFFFF, i1 = mc.x >> 16;
        const int i2 = mc.y & 0xFFFF, i3 = mc.y >> 16;
        const int i4 = mc.z & 0xFFFF, i5 = mc.z >> 16;
        const int hh = mc.w & 0xFFFF;
        // 12 independent gathers (y-form)
        float y00 = vrow[0][i0], y01 = vrow[0][i1], y02 = vrow[0][i2];
        float y03 = vrow[0][i3], y04 = vrow[0][i4], y05 = vrow[0][i5];
        float y10 = vrow[1][i0], y11 = vrow[1][i1], y12 = vrow[1][i2];
        float y13 = vrow[1][i3], y14 = vrow[1][i4], y15 = vrow[1][i5];

        float ym0 = fmaxf(fmaxf(fmaxf(y00, y01), fmaxf(y02, y03)), fmaxf(y04, y05));
        float ym1 = fmaxf(fmaxf(fmaxf(y10, y11), fmaxf(y12, y13)), fmaxf(y14, y15));
        float s0 = exp2f(y00 - ym0) + exp2f(y01 - ym0) + exp2f(y02 - ym0)
                 + exp2f(y03 - ym0) + exp2f(y04 - ym0) + exp2f(y05 - ym0);
        float s1 = exp2f(y10 - ym1) + exp2f(y11 - ym1) + exp2f(y12 - ym1)
                 + exp2f(y13 - ym1) + exp2f(y14 - ym1) + exp2f(y15 - ym1);
        float gg0 = (ym0 + __log2f(s0)) * (-K2 * ga);
        float gg1 = (ym1 + __log2f(s1)) * (-K2 * gb);
        o0p[rr] = f2bf(gg0);
        o1p[rr] = f2bf(gg1);
        if (hh < M_DIM) {
            atomicAdd(&shead[0][hh], exp2f(gg0 * C2));
            atomicAdd(&shead[1][hh], exp2f(gg1 * C2));
        }
        mc = mn; ga = gan; gb = gbn;
    }
    __syncthreads();

    // phase 3: val_new columns of out (reconstruct val = -K2*y)
    #pragma unroll
    for (int r = 0; r < NB; r++) {
        const int c = tid;
        float4 y = ((const float4*)vrow[r])[c];
        float4 v;
        v.x = -K2 * y.x; v.y = -K2 * y.y; v.z = -K2 * y.z; v.w = -K2 * y.w;
        if (c < M_DIM / 4) {
            int p = c * 4;
            float s0 = shead[r][p], s1 = shead[r][p+1], s2 = shead[r][p+2], s3 = shead[r][p+3];
            if (s0 > 0.0f) v.x = fmaxf(v.x, K3 * __log2f(s0));
            if (s1 > 0.0f) v.y = fmaxf(v.y, K3 * __log2f(s1));
            if (s2 > 0.0f) v.z = fmaxf(v.z, K3 * __log2f(s2));
            if (s3 > 0.0f) v.w = fmaxf(v.w, K3 * __log2f(s3));
        }
        ((float4*)(outp + (size_t)(b0 + r) * OUT_STRIDE))[c] = v;
    }
}

// ---------------------------------------------------------------------------
// global_load_lds 16B staging, XOR-swizzled source, linear LDS dest.
// CH = 16B chunks per row (8 for BK=64, 16 for BK=128).
// ---------------------------------------------------------------------------
template<int CH>
__device__ __forceinline__ void stage16(unsigned short* lds,
                                        const unsigned short* gsrc,
                                        int K, int c)
{
    const int row = c / CH, slot = c % CH;
    const int k8 = slot ^ (row & (CH - 1));   // logical chunk at this slot
    __builtin_amdgcn_global_load_lds(
        (const __attribute__((address_space(1))) void*)(gsrc + (size_t)row * K + k8 * 8),
        (__attribute__((address_space(3))) void*)(lds + c * 8), 16, 0, 0);
}

// ---------------------------------------------------------------------------
// Main split-K GEMM: BM=64, BN=64, BK=128, 4 waves, grid (32,8,4)=1024
// -> 4 blocks/CU, 16 waves/CU. part[z][m][n] f32.
// ---------------------------------------------------------------------------
__global__ __launch_bounds__(256, 4) void gemm_main(
    const unsigned short* __restrict__ Ag,
    const unsigned short* __restrict__ Btg,
    float* __restrict__ part, int K, int NS)
{
    __shared__ __align__(16) unsigned short Alds[64 * 128];
    __shared__ __align__(16) unsigned short Blds[64 * 128];
    const int Kc = K / gridDim.z;
    const int k0 = blockIdx.z * Kc;
    part += (size_t)blockIdx.z * B_DIM * NS;
    const int m0 = blockIdx.x * 64, n0 = blockIdx.y * 64;
    const int tid = threadIdx.x;
    const int lane = tid & 63, wid = tid >> 6;
    const int wr = wid >> 1, wc = wid & 1;
    f32x4 acc[2][2] = {};

    for (int kt = 0; kt < Kc; kt += 128) {
        const unsigned short* Ab = Ag  + (size_t)m0 * K + k0 + kt;
        const unsigned short* Bb = Btg + (size_t)n0 * K + k0 + kt;
        #pragma unroll
        for (int q = 0; q < 4; q++) {
            stage16<16>(Alds, Ab, K, tid + q * 256);
            stage16<16>(Blds, Bb, K, tid + q * 256);
        }
        __syncthreads();
        #pragma unroll
        for (int ks = 0; ks < 4; ks++) {
            const int k8 = ks * 4 + (lane >> 4);
            const int r0a = wr * 32 + (lane & 15);
            const int r0b = wc * 32 + (lane & 15);
            const int sa = (k8 ^ (r0a & 15)) << 3;
            const int sb = (k8 ^ (r0b & 15)) << 3;
            short8 a0 = *(const short8*)&Alds[(r0a)      * 128 + sa];
            short8 a1 = *(const short8*)&Alds[(r0a + 16) * 128 + sa];
            short8 b0 = *(const short8*)&Blds[(r0b)      * 128 + sb];
            short8 b1 = *(const short8*)&Blds[(r0b + 16) * 128 + sb];
            acc[0][0] = __builtin_amdgcn_mfma_f32_16x16x32_bf16(a0, b0, acc[0][0], 0, 0, 0);
            acc[0][1] = __builtin_amdgcn_mfma_f32_16x16x32_bf16(a0, b1, acc[0][1], 0, 0, 0);
            acc[1][0] = __builtin_amdgcn_mfma_f32_16x16x32_bf16(a1, b0, acc[1][0], 0, 0, 0);
            acc[1][1] = __builtin_amdgcn_mfma_f32_16x16x32_bf16(a1, b1, acc[1][1], 0, 0, 0);
        }
        __syncthreads();
    }

    const int rbase = (lane >> 4) * 4;
    const int cbase = lane & 15;
    #pragma unroll
    for (int i = 0; i < 2; i++) {
        #pragma unroll
        for (int j = 0; j < 2; j++) {
            const int gn = n0 + wc * 32 + j * 16 + cbase;
            #pragma unroll
            for (int q = 0; q < 4; q++) {
                const int gm = m0 + wr * 32 + i * 16 + rbase + q;
                part[(size_t)gm * NS + gn] = acc[i][j][q];
            }
        }
    }
}

// ---------------------------------------------------------------------------
// Small split-K GEMM (lam_ment): 64x64 tile, BK=64, z=4 (Kc=64, 1 K-iter).
// ---------------------------------------------------------------------------
__global__ __launch_bounds__(256, 4) void gemm_lam(
    const unsigned short* __restrict__ Ag,
    const unsigned short* __restrict__ Btg,
    float* __restrict__ part, int K, int NS)
{
    __shared__ __align__(16) unsigned short Alds[64 * 64];
    __shared__ __align__(16) unsigned short Blds[64 * 64];
    const int Kc = K / gridDim.z;
    const int k0 = blockIdx.z * Kc;
    part += (size_t)blockIdx.z * B_DIM * NS;
    const int m0 = blockIdx.x * 64, n0 = blockIdx.y * 64;
    const int tid = threadIdx.x;
    const int lane = tid & 63, wid = tid >> 6;
    const int wr = wid >> 1, wc = wid & 1;
    f32x4 acc[2][2] = {};

    for (int kt = 0; kt < Kc; kt += 64) {
        const unsigned short* Ab = Ag  + (size_t)m0 * K + k0 + kt;
        const unsigned short* Bb = Btg + (size_t)n0 * K + k0 + kt;
        stage16<8>(Alds, Ab, K, tid);
        stage16<8>(Alds, Ab, K, tid + 256);
        stage16<8>(Blds, Bb, K, tid);
        stage16<8>(Blds, Bb, K, tid + 256);
        __syncthreads();
        #pragma unroll
        for (int ks = 0; ks < 2; ks++) {
            const int k8 = ks * 4 + (lane >> 4);
            const int r0a = wr * 32 + (lane & 15);
            const int r0b = wc * 32 + (lane & 15);
            const int sa = (k8 ^ (r0a & 7)) << 3;
            const int sb = (k8 ^ (r0b & 7)) << 3;
            short8 a0 = *(const short8*)&Alds[(r0a)      * 64 + sa];
            short8 a1 = *(const short8*)&Alds[(r0a + 16) * 64 + sa];
            short8 b0 = *(const short8*)&Blds[(r0b)      * 64 + sb];
            short8 b1 = *(const short8*)&Blds[(r0b + 16) * 64 + sb];
            acc[0][0] = __builtin_amdgcn_mfma_f32_16x16x32_bf16(a0, b0, acc[0][0], 0, 0, 0);
            acc[0][1] = __builtin_amdgcn_mfma_f32_16x16x32_bf16(a0, b1, acc[0][1], 0, 0, 0);
            acc[1][0] = __builtin_amdgcn_mfma_f32_16x16x32_bf16(a1, b0, acc[1][0], 0, 0, 0);
            acc[1][1] = __builtin_amdgcn_mfma_f32_16x16x32_bf16(a1, b1, acc[1][1], 0, 0, 0);
        }
        __syncthreads();
    }

    const int rbase = (lane >> 4) * 4;
    const int cbase = lane & 15;
    #pragma unroll
    for (int i = 0; i < 2; i++) {
        #pragma unroll
        for (int j = 0; j < 2; j++) {
            const int gn = n0 + wc * 32 + j * 16 + cbase;
            #pragma unroll
            for (int q = 0; q < 4; q++) {
                const int gm = m0 + wr * 32 + i * 16 + rbase + q;
                part[(size_t)gm * NS + gn] = acc[i][j][q];
            }
        }
    }
}

// ---------------------------------------------------------------------------
// Epilogue: sum split-K partials; relu(main); lam cols += softplus(b+lam_ment)
// ---------------------------------------------------------------------------
__global__ __launch_bounds__(256) void epilogue(
    const float* __restrict__ mainpart, const float* __restrict__ lampart,
    const float* __restrict__ bvec, float* __restrict__ outp)
{
    const int idx = blockIdx.x * 256 + threadIdx.x;   // over 2048*128
    const int m = idx >> 7, n4 = idx & 127;
    const size_t mb = (size_t)m * 128 + n4;           // float4 units (NS=512)
    const size_t zs = (size_t)B_DIM * 128;
    float4 s = ((const float4*)mainpart)[mb];
    #pragma unroll
    for (int z = 1; z < 4; z++) {
        float4 t = ((const float4*)mainpart)[mb + z * zs];
        s.x += t.x; s.y += t.y; s.z += t.z; s.w += t.w;
    }
    s.x = fmaxf(s.x, 0.0f); s.y = fmaxf(s.y, 0.0f);
    s.z = fmaxf(s.z, 0.0f); s.w = fmaxf(s.w, 0.0f);
    if (n4 >= 64) {
        const int na = n4 - 64;                       // float4 idx in 256-col lam
        const size_t lb = (size_t)m * 64 + na;
        const size_t ls = (size_t)B_DIM * 64;
        float4 l0 = ((const float4*)lampart)[lb];
        #pragma unroll
        for (int z = 1; z < 4; z++) {
            float4 t = ((const float4*)lampart)[lb + z * ls];
            l0.x += t.x; l0.y += t.y; l0.z += t.z; l0.w += t.w;
        }
        float4 bb = ((const float4*)bvec)[na];
        float x0 = bb.x + l0.x, x1 = bb.y + l0.y;
        float x2 = bb.z + l0.z, x3 = bb.w + l0.w;
        s.x += (x0 > 20.0f) ? x0 : log1pf(__expf(x0));
        s.y += (x1 > 20.0f) ? x1 : log1pf(__expf(x1));
        s.z += (x2 > 20.0f) ? x2 : log1pf(__expf(x2));
        s.w += (x3 > 20.0f) ? x3 : log1pf(__expf(x3));
    }
    ((float4*)(outp + (size_t)m * OUT_STRIDE + 2048))[n4] = s;
}

// ---------------------------------------------------------------------------
extern "C" void kernel_launch(void* const* d_in, const int* in_sizes, int n_in,
                              void* d_out, int out_size, void* d_ws, size_t ws_size,
                              hipStream_t stream)
{
    const float* M_minus = (const float*)d_in[0];
    const float* amask   = (const float*)d_in[1];
    const float* gate    = (const float*)d_in[2];
    const float* bmask   = (const float*)d_in[3];
    const float* isM     = (const float*)d_in[4];
    const float* isA     = (const float*)d_in[5];
    const float* GA      = (const float*)d_in[6];
    const float* GB      = (const float*)d_in[7];
    const float* bvec    = (const float*)d_in[8];
    const float* w       = (const float*)d_in[9];
    const int*   bidx    = (const int*)d_in[10];
    const int*   hidx    = (const int*)d_in[11];
    float* outp = (float*)d_out;

    char* ws = (char*)d_ws;
    unsigned short* g_bf   = (unsigned short*)(ws + 0);          // 16 MiB
    unsigned short* GAT    = (unsigned short*)(ws + (16u<<20));  // 2 MiB
    unsigned short* GBT    = (unsigned short*)(ws + (18u<<20));  // 2 MiB (contiguous after GAT)
    unsigned short* w_bf   = (unsigned short*)(ws + (20u<<20));  // 128 KiB
    uint4*          meta   = (uint4*)(ws + (20u<<20) + (256u<<10)); // 64 KiB
    unsigned short* mclip  = (unsigned short*)(ws + (21u<<20));  // 1 MiB
    float*          mainp  = (float*)(ws + (22u<<20));           // 4 x 4 MiB
    float*          lamp   = (float*)(ws + (38u<<20));           // 4 x 2 MiB

    prep_all<<<dim3(2320), dim3(256), 0, stream>>>(
        GA, GB, isM, isA, w, bidx, bmask, hidx, GAT, GBT, w_bf, meta);
    main_fused<<<dim3(B_DIM / NB), dim3(512), 0, stream>>>(
        M_minus, amask, gate, meta, g_bf, mclip, outp);
    // lam_ment partials: Mclip @ w^T, K=256 split 4 (Kc=64)
    gemm_lam<<<dim3(B_DIM / 64, A_DIM / 64, 4), dim3(256), 0, stream>>>(
        mclip, w_bf, lamp, M_DIM, A_DIM);
    // [S | lam_logic] partials: g @ [GAT|GBT]^T, K=4096 split 4 -> 1024 blocks
    gemm_main<<<dim3(B_DIM / 64, 512 / 64, 4), dim3(256), 0, stream>>>(
        g_bf, GAT, mainp, R_DIM, 512);
    epilogue<<<dim3((B_DIM * 128) / 256), dim3(256), 0, stream>>>(
        mainp, lamp, bvec, outp);
}

// Round 7
// 54.956 us; speedup vs baseline: 1.1314x; 1.1314x over previous
//
#include <hip/hip_runtime.h>

typedef __attribute__((ext_vector_type(8))) short short8;
typedef __attribute__((ext_vector_type(4))) float f32x4;

#define B_DIM 2048
#define P_DIM 2048
#define R_DIM 4096
#define H_DIM 6
#define M_DIM 256
#define A_DIM 256
#define OUT_STRIDE 2560   // P + M + A
#define NB 2              // batch rows per main_fused block
#define VSTRIDE 2064      // vrow row stride (sentinel at 2048; +16 bank offset)

// exp2-form constants: y = -C1*val;  g = -K2*(ymax+log2 s)*gate
#define C1 14.426950408889634f   // 10/ln2
#define K2 0.06931471805599453f  // ln2/10
#define C2 7.213475204444817f    // 5/ln2
#define K3 0.13862943611198906f  // ln2/5

static __device__ __forceinline__ float fexp2(float x) { return __builtin_amdgcn_exp2f(x); }
static __device__ __forceinline__ float flog2(float x) { return __builtin_amdgcn_logf(x); }

static __device__ __forceinline__ unsigned short f2bf(float f) {
    unsigned u = __builtin_bit_cast(unsigned, f);
    u += 0x7fffu + ((u >> 16) & 1u);          // round-to-nearest-even
    return (unsigned short)(u >> 16);
}

// ---------------------------------------------------------------------------
// prep_all: one launch, block-range branching.
//   bid <  2048 : transpose+scale GA/GB -> GAT/GBT (bf16, N x K)
//   2048..2303  : cast w -> bf16
//   2304..2319  : pack rule metadata (6x u16 idx, masked -> 2048; u16 head)
// ---------------------------------------------------------------------------
__global__ __launch_bounds__(256) void prep_all(
    const float* __restrict__ GA, const float* __restrict__ GB,
    const float* __restrict__ isM, const float* __restrict__ isA,
    const float* __restrict__ w,
    const int* __restrict__ bidx, const float* __restrict__ bmask,
    const int* __restrict__ hidx,
    unsigned short* __restrict__ GAT, unsigned short* __restrict__ GBT,
    unsigned short* __restrict__ wb, uint4* __restrict__ meta)
{
    __shared__ float t[32][33];
    const int bid = blockIdx.x;
    if (bid < 2048) {
        const int which = bid >> 10;
        const int rem = bid & 1023;
        const float* src = which ? GB : GA;
        const float* scv = which ? isA : isM;
        unsigned short* dst = which ? GBT : GAT;
        const int r0 = (rem >> 3) * 32;   // K (=R) dim
        const int n0 = (rem & 7) * 32;    // N (=256) dim
        const int tx = threadIdx.x & 31, ty = threadIdx.x >> 5;
        #pragma unroll
        for (int q = 0; q < 4; q++) {
            int rr = ty + q * 8;
            t[rr][tx] = scv[r0 + rr] * src[(size_t)(r0 + rr) * 256 + n0 + tx];
        }
        __syncthreads();
        #pragma unroll
        for (int q = 0; q < 4; q++) {
            int nn = ty + q * 8;
            dst[(size_t)(n0 + nn) * R_DIM + r0 + tx] = f2bf(t[tx][nn]);
        }
    } else if (bid < 2304) {
        const int i = (bid - 2048) * 256 + threadIdx.x;   // 65536
        wb[i] = f2bf(w[i]);
    } else {
        const int r = (bid - 2304) * 256 + threadIdx.x;   // 4096
        const int* bi = bidx + r * H_DIM;
        const float* bm = bmask + r * H_DIM;
        unsigned s[H_DIM];
        #pragma unroll
        for (int h = 0; h < H_DIM; h++)
            s[h] = (bm[h] > 0.0f) ? (unsigned)bi[h] : 2048u;
        const int hh = hidx[r];
        unsigned sh = (hh < M_DIM) ? (unsigned)hh : 0xFFFFu;
        uint4 m;
        m.x = s[0] | (s[1] << 16);
        m.y = s[2] | (s[3] << 16);
        m.z = s[4] | (s[5] << 16);
        m.w = sh;
        meta[r] = m;
    }
}

// ---------------------------------------------------------------------------
// Main fused kernel: NB=2 rows/block, 1024 threads (16 waves), grid 1024
// -> 2 blocks/CU = 32 waves/CU, only 4 rule-iterations per thread.
// vrow stored as y = -C1*val so soft-min = max + exp2.
// ---------------------------------------------------------------------------
__global__ __launch_bounds__(1024, 8) void main_fused(
    const float* __restrict__ M_minus, const float* __restrict__ amask,
    const float* __restrict__ gate,    const uint4* __restrict__ meta,
    unsigned short* __restrict__ g_bf, unsigned short* __restrict__ mclip_bf,
    float* __restrict__ outp)
{
    __shared__ float vrow[NB][VSTRIDE];
    __shared__ float shead[NB][M_DIM];
    const int b0 = blockIdx.x * NB;
    const int tid = threadIdx.x;          // 0..1023
    const int pr = tid >> 9;              // row (phase 1/3)
    const int pc = tid & 511;             // float4 col (phase 1/3)

    if (tid < NB * M_DIM) shead[tid >> 8][tid & 255] = 0.0f;
    if (tid < NB) vrow[tid][2048] = -1.0e9f;   // sentinel (masked bodies)

    // phase 1: each thread builds one float4 of one row (1024 = 2 x 512)
    {
        float4 v = ((const float4*)(amask + (size_t)(b0 + pr) * P_DIM))[pc];
        if (pc < M_DIM / 4) {
            float4 m = ((const float4*)(M_minus + (size_t)(b0 + pr) * M_DIM))[pc];
            float mc0 = fminf(fmaxf(m.x, 0.0f), 1.0f);
            float mc1 = fminf(fmaxf(m.y, 0.0f), 1.0f);
            float mc2 = fminf(fmaxf(m.z, 0.0f), 1.0f);
            float mc3 = fminf(fmaxf(m.w, 0.0f), 1.0f);
            ushort4 mb; mb.x = f2bf(mc0); mb.y = f2bf(mc1); mb.z = f2bf(mc2); mb.w = f2bf(mc3);
            ((ushort4*)(mclip_bf + (size_t)(b0 + pr) * M_DIM))[pc] = mb;
            v.x = fmaxf(mc0, v.x); v.y = fmaxf(mc1, v.y);
            v.z = fmaxf(mc2, v.z); v.w = fmaxf(mc3, v.w);
        }
        float4 y;
        y.x = -C1 * v.x; y.y = -C1 * v.y; y.z = -C1 * v.z; y.w = -C1 * v.w;
        ((float4*)vrow[pr])[pc] = y;
    }
    __syncthreads();

    // phase 2: rules, 4 iterations (4096/1024), prefetch distance 1
    const float* g0p = gate + (size_t)b0 * R_DIM;
    const float* g1p = gate + (size_t)(b0 + 1) * R_DIM;
    unsigned short* o0p = g_bf + (size_t)b0 * R_DIM;
    unsigned short* o1p = g_bf + (size_t)(b0 + 1) * R_DIM;

    uint4 mc = meta[tid];
    float ga = g0p[tid], gb = g1p[tid];
    #pragma unroll
    for (int it = 0; it < R_DIM / 1024; it++) {
        const int rr = tid + it * 1024;
        uint4 mn = mc; float gan = ga, gbn = gb;
        if (it < R_DIM / 1024 - 1) {
            mn  = meta[rr + 1024];
            gan = g0p[rr + 1024];
            gbn = g1p[rr + 1024];
        }
        const int i0 = mc.x & 0xFFFF, i1 = mc.x >> 16;
        const int i2 = mc.y & 0xFFFF, i3 = mc.y >> 16;
        const int i4 = mc.z & 0xFFFF, i5 = mc.z >> 16;
        const int hh = mc.w & 0xFFFF;
        // 12 independent gathers (y-form)
        float y00 = vrow[0][i0], y01 = vrow[0][i1], y02 = vrow[0][i2];
        float y03 = vrow[0][i3], y04 = vrow[0][i4], y05 = vrow[0][i5];
        float y10 = vrow[1][i0], y11 = vrow[1][i1], y12 = vrow[1][i2];
        float y13 = vrow[1][i3], y14 = vrow[1][i4], y15 = vrow[1][i5];

        float ym0 = fmaxf(fmaxf(fmaxf(y00, y01), fmaxf(y02, y03)), fmaxf(y04, y05));
        float ym1 = fmaxf(fmaxf(fmaxf(y10, y11), fmaxf(y12, y13)), fmaxf(y14, y15));
        float s0 = fexp2(y00 - ym0) + fexp2(y01 - ym0) + fexp2(y02 - ym0)
                 + fexp2(y03 - ym0) + fexp2(y04 - ym0) + fexp2(y05 - ym0);
        float s1 = fexp2(y10 - ym1) + fexp2(y11 - ym1) + fexp2(y12 - ym1)
                 + fexp2(y13 - ym1) + fexp2(y14 - ym1) + fexp2(y15 - ym1);
        float gg0 = (ym0 + flog2(s0)) * (-K2 * ga);
        float gg1 = (ym1 + flog2(s1)) * (-K2 * gb);
        o0p[rr] = f2bf(gg0);
        o1p[rr] = f2bf(gg1);
        if (hh < M_DIM) {
            atomicAdd(&shead[0][hh], fexp2(gg0 * C2));
            atomicAdd(&shead[1][hh], fexp2(gg1 * C2));
        }
        mc = mn; ga = gan; gb = gbn;
    }
    __syncthreads();

    // phase 3: val_new columns of out (reconstruct val = -K2*y)
    {
        float4 y = ((const float4*)vrow[pr])[pc];
        float4 v;
        v.x = -K2 * y.x; v.y = -K2 * y.y; v.z = -K2 * y.z; v.w = -K2 * y.w;
        if (pc < M_DIM / 4) {
            int p = pc * 4;
            float s0 = shead[pr][p], s1 = shead[pr][p+1];
            float s2 = shead[pr][p+2], s3 = shead[pr][p+3];
            if (s0 > 0.0f) v.x = fmaxf(v.x, K3 * flog2(s0));
            if (s1 > 0.0f) v.y = fmaxf(v.y, K3 * flog2(s1));
            if (s2 > 0.0f) v.z = fmaxf(v.z, K3 * flog2(s2));
            if (s3 > 0.0f) v.w = fmaxf(v.w, K3 * flog2(s3));
        }
        ((float4*)(outp + (size_t)(b0 + pr) * OUT_STRIDE))[pc] = v;
    }
}

// ---------------------------------------------------------------------------
// global_load_lds 16B staging, XOR-swizzled source, linear LDS dest. BK=128.
// ---------------------------------------------------------------------------
__device__ __forceinline__ void stage16(unsigned short* lds,
                                        const unsigned short* gsrc,
                                        int K, int c)
{
    const int row = c >> 4, slot = c & 15;
    const int k8 = slot ^ (row & 15);      // logical 16B chunk at this slot
    __builtin_amdgcn_global_load_lds(
        (const __attribute__((address_space(1))) void*)(gsrc + (size_t)row * K + k8 * 8),
        (__attribute__((address_space(3))) void*)(lds + c * 8), 16, 0, 0);
}

// ---------------------------------------------------------------------------
// Main split-K GEMM: BM=128, BN=64, BK=128, 4 waves (wave tile 64x32).
// grid (16, 8, 4) = 512 blocks. part[z][m][n] f32.
// ---------------------------------------------------------------------------
__global__ __launch_bounds__(256) void gemm_main(
    const unsigned short* __restrict__ Ag,
    const unsigned short* __restrict__ Btg,
    float* __restrict__ part, int K, int NS)
{
    __shared__ __align__(16) unsigned short Alds[128 * 128];
    __shared__ __align__(16) unsigned short Blds[64 * 128];
    const int Kc = K / gridDim.z;
    const int k0 = blockIdx.z * Kc;
    part += (size_t)blockIdx.z * B_DIM * NS;
    const int m0 = blockIdx.x * 128, n0 = blockIdx.y * 64;
    const int tid = threadIdx.x;
    const int lane = tid & 63, wid = tid >> 6;
    const int wr = wid >> 1, wc = wid & 1;
    f32x4 acc[4][2] = {};

    for (int kt = 0; kt < Kc; kt += 128) {
        const unsigned short* Ab = Ag  + (size_t)m0 * K + k0 + kt;
        const unsigned short* Bb = Btg + (size_t)n0 * K + k0 + kt;
        #pragma unroll
        for (int q = 0; q < 8; q++) stage16(Alds, Ab, K, tid + q * 256);
        #pragma unroll
        for (int q = 0; q < 4; q++) stage16(Blds, Bb, K, tid + q * 256);
        __syncthreads();
        #pragma unroll
        for (int ks = 0; ks < 4; ks++) {
            const int k8 = ks * 4 + (lane >> 4);
            const int ra = wr * 64 + (lane & 15);
            const int rb = wc * 32 + (lane & 15);
            const int sa = (k8 ^ (ra & 15)) << 3;
            const int sb = (k8 ^ (rb & 15)) << 3;
            short8 a0 = *(const short8*)&Alds[(ra)      * 128 + sa];
            short8 a1 = *(const short8*)&Alds[(ra + 16) * 128 + sa];
            short8 a2 = *(const short8*)&Alds[(ra + 32) * 128 + sa];
            short8 a3 = *(const short8*)&Alds[(ra + 48) * 128 + sa];
            short8 b0 = *(const short8*)&Blds[(rb)      * 128 + sb];
            short8 b1 = *(const short8*)&Blds[(rb + 16) * 128 + sb];
            acc[0][0] = __builtin_amdgcn_mfma_f32_16x16x32_bf16(a0, b0, acc[0][0], 0, 0, 0);
            acc[0][1] = __builtin_amdgcn_mfma_f32_16x16x32_bf16(a0, b1, acc[0][1], 0, 0, 0);
            acc[1][0] = __builtin_amdgcn_mfma_f32_16x16x32_bf16(a1, b0, acc[1][0], 0, 0, 0);
            acc[1][1] = __builtin_amdgcn_mfma_f32_16x16x32_bf16(a1, b1, acc[1][1], 0, 0, 0);
            acc[2][0] = __builtin_amdgcn_mfma_f32_16x16x32_bf16(a2, b0, acc[2][0], 0, 0, 0);
            acc[2][1] = __builtin_amdgcn_mfma_f32_16x16x32_bf16(a2, b1, acc[2][1], 0, 0, 0);
            acc[3][0] = __builtin_amdgcn_mfma_f32_16x16x32_bf16(a3, b0, acc[3][0], 0, 0, 0);
            acc[3][1] = __builtin_amdgcn_mfma_f32_16x16x32_bf16(a3, b1, acc[3][1], 0, 0, 0);
        }
        __syncthreads();
    }

    const int rbase = (lane >> 4) * 4;
    const int cbase = lane & 15;
    #pragma unroll
    for (int i = 0; i < 4; i++) {
        #pragma unroll
        for (int j = 0; j < 2; j++) {
            const int gn = n0 + wc * 32 + j * 16 + cbase;
            #pragma unroll
            for (int q = 0; q < 4; q++) {
                const int gm = m0 + wr * 64 + i * 16 + rbase + q;
                part[(size_t)gm * NS + gn] = acc[i][j][q];
            }
        }
    }
}

// ---------------------------------------------------------------------------
// Small split-K GEMM (lam_ment): 64x64 tile, BK=128, z=2 (Kc=128, 1 K-iter).
// ---------------------------------------------------------------------------
__global__ __launch_bounds__(256) void gemm_lam(
    const unsigned short* __restrict__ Ag,
    const unsigned short* __restrict__ Btg,
    float* __restrict__ part, int K, int NS)
{
    __shared__ __align__(16) unsigned short Alds[64 * 128];
    __shared__ __align__(16) unsigned short Blds[64 * 128];
    const int Kc = K / gridDim.z;
    const int k0 = blockIdx.z * Kc;
    part += (size_t)blockIdx.z * B_DIM * NS;
    const int m0 = blockIdx.x * 64, n0 = blockIdx.y * 64;
    const int tid = threadIdx.x;
    const int lane = tid & 63, wid = tid >> 6;
    const int wr = wid >> 1, wc = wid & 1;
    f32x4 acc[2][2] = {};

    for (int kt = 0; kt < Kc; kt += 128) {
        const unsigned short* Ab = Ag  + (size_t)m0 * K + k0 + kt;
        const unsigned short* Bb = Btg + (size_t)n0 * K + k0 + kt;
        #pragma unroll
        for (int q = 0; q < 4; q++) {
            stage16(Alds, Ab, K, tid + q * 256);
            stage16(Blds, Bb, K, tid + q * 256);
        }
        __syncthreads();
        #pragma unroll
        for (int ks = 0; ks < 4; ks++) {
            const int k8 = ks * 4 + (lane >> 4);
            const int r0a = wr * 32 + (lane & 15);
            const int r0b = wc * 32 + (lane & 15);
            const int sa = (k8 ^ (r0a & 15)) << 3;
            const int sb = (k8 ^ (r0b & 15)) << 3;
            short8 a0 = *(const short8*)&Alds[(r0a)      * 128 + sa];
            short8 a1 = *(const short8*)&Alds[(r0a + 16) * 128 + sa];
            short8 b0 = *(const short8*)&Blds[(r0b)      * 128 + sb];
            short8 b1 = *(const short8*)&Blds[(r0b + 16) * 128 + sb];
            acc[0][0] = __builtin_amdgcn_mfma_f32_16x16x32_bf16(a0, b0, acc[0][0], 0, 0, 0);
            acc[0][1] = __builtin_amdgcn_mfma_f32_16x16x32_bf16(a0, b1, acc[0][1], 0, 0, 0);
            acc[1][0] = __builtin_amdgcn_mfma_f32_16x16x32_bf16(a1, b0, acc[1][0], 0, 0, 0);
            acc[1][1] = __builtin_amdgcn_mfma_f32_16x16x32_bf16(a1, b1, acc[1][1], 0, 0, 0);
        }
        __syncthreads();
    }

    const int rbase = (lane >> 4) * 4;
    const int cbase = lane & 15;
    #pragma unroll
    for (int i = 0; i < 2; i++) {
        #pragma unroll
        for (int j = 0; j < 2; j++) {
            const int gn = n0 + wc * 32 + j * 16 + cbase;
            #pragma unroll
            for (int q = 0; q < 4; q++) {
                const int gm = m0 + wr * 32 + i * 16 + rbase + q;
                part[(size_t)gm * NS + gn] = acc[i][j][q];
            }
        }
    }
}

// ---------------------------------------------------------------------------
// Epilogue: sum split-K partials; relu(main); lam cols += softplus(b+lam_ment)
// ---------------------------------------------------------------------------
__global__ __launch_bounds__(256) void epilogue(
    const float* __restrict__ mainpart, const float* __restrict__ lampart,
    const float* __restrict__ bvec, float* __restrict__ outp)
{
    const int idx = blockIdx.x * 256 + threadIdx.x;   // over 2048*128
    const int m = idx >> 7, n4 = idx & 127;
    const size_t mb = (size_t)m * 128 + n4;           // float4 units (NS=512)
    const size_t zs = (size_t)B_DIM * 128;
    float4 s = ((const float4*)mainpart)[mb];
    #pragma unroll
    for (int z = 1; z < 4; z++) {
        float4 t = ((const float4*)mainpart)[mb + z * zs];
        s.x += t.x; s.y += t.y; s.z += t.z; s.w += t.w;
    }
    s.x = fmaxf(s.x, 0.0f); s.y = fmaxf(s.y, 0.0f);
    s.z = fmaxf(s.z, 0.0f); s.w = fmaxf(s.w, 0.0f);
    if (n4 >= 64) {
        const int na = n4 - 64;                       // float4 idx in 256-col lam
        const size_t lb = (size_t)m * 64 + na;
        float4 l0 = ((const float4*)lampart)[lb];
        float4 l1 = ((const float4*)lampart)[lb + (size_t)B_DIM * 64];
        float4 bb = ((const float4*)bvec)[na];
        float x0 = bb.x + l0.x + l1.x, x1 = bb.y + l0.y + l1.y;
        float x2 = bb.z + l0.z + l1.z, x3 = bb.w + l0.w + l1.w;
        s.x += (x0 > 20.0f) ? x0 : log1pf(__expf(x0));
        s.y += (x1 > 20.0f) ? x1 : log1pf(__expf(x1));
        s.z += (x2 > 20.0f) ? x2 : log1pf(__expf(x2));
        s.w += (x3 > 20.0f) ? x3 : log1pf(__expf(x3));
    }
    ((float4*)(outp + (size_t)m * OUT_STRIDE + 2048))[n4] = s;
}

// ---------------------------------------------------------------------------
extern "C" void kernel_launch(void* const* d_in, const int* in_sizes, int n_in,
                              void* d_out, int out_size, void* d_ws, size_t ws_size,
                              hipStream_t stream)
{
    const float* M_minus = (const float*)d_in[0];
    const float* amask   = (const float*)d_in[1];
    const float* gate    = (const float*)d_in[2];
    const float* bmask   = (const float*)d_in[3];
    const float* isM     = (const float*)d_in[4];
    const float* isA     = (const float*)d_in[5];
    const float* GA      = (const float*)d_in[6];
    const float* GB      = (const float*)d_in[7];
    const float* bvec    = (const float*)d_in[8];
    const float* w       = (const float*)d_in[9];
    const int*   bidx    = (const int*)d_in[10];
    const int*   hidx    = (const int*)d_in[11];
    float* outp = (float*)d_out;

    char* ws = (char*)d_ws;
    unsigned short* g_bf   = (unsigned short*)(ws + 0);          // 16 MiB
    unsigned short* GAT    = (unsigned short*)(ws + (16u<<20));  // 2 MiB
    unsigned short* GBT    = (unsigned short*)(ws + (18u<<20));  // 2 MiB (contiguous after GAT)
    unsigned short* w_bf   = (unsigned short*)(ws + (20u<<20));  // 128 KiB
    uint4*          meta   = (uint4*)(ws + (20u<<20) + (256u<<10)); // 64 KiB
    unsigned short* mclip  = (unsigned short*)(ws + (21u<<20));  // 1 MiB
    float*          mainp  = (float*)(ws + (22u<<20));           // 4 x 4 MiB
    float*          lamp   = (float*)(ws + (38u<<20));           // 2 x 2 MiB

    prep_all<<<dim3(2320), dim3(256), 0, stream>>>(
        GA, GB, isM, isA, w, bidx, bmask, hidx, GAT, GBT, w_bf, meta);
    main_fused<<<dim3(B_DIM / NB), dim3(1024), 0, stream>>>(
        M_minus, amask, gate, meta, g_bf, mclip, outp);
    // lam_ment partials: Mclip @ w^T, K=256 split 2 (Kc=128)
    gemm_lam<<<dim3(B_DIM / 64, A_DIM / 64, 2), dim3(256), 0, stream>>>(
        mclip, w_bf, lamp, M_DIM, A_DIM);
    // [S | lam_logic] partials: g @ [GAT|GBT]^T, K=4096 split 4 -> 512 blocks
    gemm_main<<<dim3(B_DIM / 128, 512 / 64, 4), dim3(256), 0, stream>>>(
        g_bf, GAT, mainp, R_DIM, 512);
    epilogue<<<dim3((B_DIM * 128) / 256), dim3(256), 0, stream>>>(
        mainp, lamp, bvec, outp);
}

// Round 8
// 50.739 us; speedup vs baseline: 1.2254x; 1.0831x over previous
//
#include <hip/hip_runtime.h>

typedef __attribute__((ext_vector_type(8))) short short8;
typedef __attribute__((ext_vector_type(4))) float f32x4;

#define B_DIM 2048
#define P_DIM 2048
#define R_DIM 4096
#define H_DIM 6
#define M_DIM 256
#define A_DIM 256
#define OUT_STRIDE 2560   // P + M + A
#define NB 2              // batch rows per main_fused block

// exp2-form constants: y = -C1*val;  g = -K2*(ymax+log2 s)*gate
#define C1 14.426950408889634f   // 10/ln2
#define K2 0.06931471805599453f  // ln2/10
#define C2 7.213475204444817f    // 5/ln2
#define K3 0.13862943611198906f  // ln2/5

static __device__ __forceinline__ float fexp2(float x) { return __builtin_amdgcn_exp2f(x); }
static __device__ __forceinline__ float flog2(float x) { return __builtin_amdgcn_logf(x); }

static __device__ __forceinline__ unsigned short f2bf(float f) {
    unsigned u = __builtin_bit_cast(unsigned, f);
    u += 0x7fffu + ((u >> 16) & 1u);          // round-to-nearest-even
    return (unsigned short)(u >> 16);
}

// ---------------------------------------------------------------------------
// prep_meta: pack rule metadata (6x u16 idx, masked -> sentinel 2048; u16
// head, 0xFFFF if >=256). Must precede main_fused (which consumes meta).
// grid 64 x 64 threads, one rule per thread.
// ---------------------------------------------------------------------------
__global__ __launch_bounds__(64) void prep_meta(
    const int* __restrict__ bidx, const float* __restrict__ bmask,
    const int* __restrict__ hidx, uint4* __restrict__ meta)
{
    const int r = blockIdx.x * 64 + threadIdx.x;   // 4096
    const int* bi = bidx + r * H_DIM;
    const float* bm = bmask + r * H_DIM;
    unsigned s[H_DIM];
    #pragma unroll
    for (int h = 0; h < H_DIM; h++)
        s[h] = (bm[h] > 0.0f) ? (unsigned)bi[h] : 2048u;
    const int hh = hidx[r];
    unsigned sh = (hh < M_DIM) ? (unsigned)hh : 0xFFFFu;
    uint4 m;
    m.x = s[0] | (s[1] << 16);
    m.y = s[2] | (s[3] << 16);
    m.z = s[4] | (s[5] << 16);
    m.w = sh;
    meta[r] = m;
}

// ---------------------------------------------------------------------------
// Main fused kernel: NB=2 rows/block, 1024 threads, grid 1024.
// Prologue (blocks 0..575): 4 prep units each (transpose+scale GA/GB tile,
// or w-cast chunk) using LDS scratch unioned with vrow.
// vrow interleaved float2 {row0,row1} -> 6 x ds_read_b64 gathers per rule.
// ---------------------------------------------------------------------------
__global__ __launch_bounds__(1024, 8) void main_fused(
    const float* __restrict__ M_minus, const float* __restrict__ amask,
    const float* __restrict__ gate,    const uint4* __restrict__ meta,
    const float* __restrict__ GA, const float* __restrict__ GB,
    const float* __restrict__ isM, const float* __restrict__ isA,
    const float* __restrict__ w,
    unsigned short* __restrict__ GAT, unsigned short* __restrict__ GBT,
    unsigned short* __restrict__ wb,
    unsigned short* __restrict__ g_bf, unsigned short* __restrict__ mclip_bf,
    float* __restrict__ outp)
{
    __shared__ __align__(16) union SM {
        struct {
            float2 vrow2[2052];          // [p] = {y(row0,p), y(row1,p)}
            float shead[NB][M_DIM];
        } mf;
        float prep[4][32][33];
    } sm;
    const int bid = blockIdx.x;
    const int tid = threadIdx.x;
    const int b0 = bid * NB;

    // ---- fused prep: 576 blocks x 4 units (2048 transpose + 256 w-cast) ----
    if (bid < 576) {
        const int s = tid >> 8, lt = tid & 255;
        const int u = bid * 4 + s;
        if (u < 2048) {
            const int which = u >> 10;
            const int rem = u & 1023;
            const float* src = which ? GB : GA;
            const float* scv = which ? isA : isM;
            const int r0 = (rem >> 3) * 32;   // K (=R) dim
            const int n0 = (rem & 7) * 32;    // N (=256) dim
            const int tx = lt & 31, ty = lt >> 5;
            #pragma unroll
            for (int q = 0; q < 4; q++) {
                int rr = ty + q * 8;
                sm.prep[s][rr][tx] = scv[r0 + rr] * src[(size_t)(r0 + rr) * 256 + n0 + tx];
            }
        } else {
            const int i = (u - 2048) * 256 + lt;   // 65536
            wb[i] = f2bf(w[i]);
        }
        __syncthreads();
        if (u < 2048) {
            const int which = u >> 10;
            const int rem = u & 1023;
            unsigned short* dst = which ? GBT : GAT;
            const int r0 = (rem >> 3) * 32;
            const int n0 = (rem & 7) * 32;
            const int tx = lt & 31, ty = lt >> 5;
            #pragma unroll
            for (int q = 0; q < 4; q++) {
                int nn = ty + q * 8;
                dst[(size_t)(n0 + nn) * R_DIM + r0 + tx] = f2bf(sm.prep[s][tx][nn]);
            }
        }
        __syncthreads();   // protect LDS reuse by mf phases
    }

    // ---- mf init ----
    if (tid < NB * M_DIM) sm.mf.shead[tid >> 8][tid & 255] = 0.0f;
    if (tid == 0) sm.mf.vrow2[2048] = make_float2(-1.0e9f, -1.0e9f);  // sentinel

    // phase 1: each thread builds p0=2t, p0+1 for both rows (interleaved)
    {
        const int p0 = tid * 2;
        float2 a0 = *(const float2*)(amask + (size_t)b0 * P_DIM + p0);
        float2 a1 = *(const float2*)(amask + (size_t)(b0 + 1) * P_DIM + p0);
        if (tid < M_DIM / 2) {
            float2 m0 = *(const float2*)(M_minus + (size_t)b0 * M_DIM + p0);
            float2 m1 = *(const float2*)(M_minus + (size_t)(b0 + 1) * M_DIM + p0);
            float mc00 = fminf(fmaxf(m0.x, 0.0f), 1.0f);
            float mc01 = fminf(fmaxf(m0.y, 0.0f), 1.0f);
            float mc10 = fminf(fmaxf(m1.x, 0.0f), 1.0f);
            float mc11 = fminf(fmaxf(m1.y, 0.0f), 1.0f);
            ushort2 w0; w0.x = f2bf(mc00); w0.y = f2bf(mc01);
            ushort2 w1; w1.x = f2bf(mc10); w1.y = f2bf(mc11);
            *(ushort2*)(mclip_bf + (size_t)b0 * M_DIM + p0) = w0;
            *(ushort2*)(mclip_bf + (size_t)(b0 + 1) * M_DIM + p0) = w1;
            a0.x = fmaxf(mc00, a0.x); a0.y = fmaxf(mc01, a0.y);
            a1.x = fmaxf(mc10, a1.x); a1.y = fmaxf(mc11, a1.y);
        }
        float4 yq;
        yq.x = -C1 * a0.x; yq.y = -C1 * a1.x;   // p0:   (row0, row1)
        yq.z = -C1 * a0.y; yq.w = -C1 * a1.y;   // p0+1: (row0, row1)
        *(float4*)&sm.mf.vrow2[p0] = yq;
    }
    __syncthreads();

    // phase 2: rules, 4 iterations, prefetch distance 1, 6 x b64 gathers
    const float* g0p = gate + (size_t)b0 * R_DIM;
    const float* g1p = gate + (size_t)(b0 + 1) * R_DIM;
    unsigned short* o0p = g_bf + (size_t)b0 * R_DIM;
    unsigned short* o1p = g_bf + (size_t)(b0 + 1) * R_DIM;

    uint4 mc = meta[tid];
    float ga = g0p[tid], gb = g1p[tid];
    #pragma unroll
    for (int it = 0; it < R_DIM / 1024; it++) {
        const int rr = tid + it * 1024;
        uint4 mn = mc; float gan = ga, gbn = gb;
        if (it < R_DIM / 1024 - 1) {
            mn  = meta[rr + 1024];
            gan = g0p[rr + 1024];
            gbn = g1p[rr + 1024];
        }
        const int i0 = mc.x & 0xFFFF, i1 = mc.x >> 16;
        const int i2 = mc.y & 0xFFFF, i3 = mc.y >> 16;
        const int i4 = mc.z & 0xFFFF, i5 = mc.z >> 16;
        const int hh = mc.w & 0xFFFF;
        float2 v0 = sm.mf.vrow2[i0], v1 = sm.mf.vrow2[i1], v2 = sm.mf.vrow2[i2];
        float2 v3 = sm.mf.vrow2[i3], v4 = sm.mf.vrow2[i4], v5 = sm.mf.vrow2[i5];

        float ym0 = fmaxf(fmaxf(fmaxf(v0.x, v1.x), fmaxf(v2.x, v3.x)), fmaxf(v4.x, v5.x));
        float ym1 = fmaxf(fmaxf(fmaxf(v0.y, v1.y), fmaxf(v2.y, v3.y)), fmaxf(v4.y, v5.y));
        float s0 = fexp2(v0.x - ym0) + fexp2(v1.x - ym0) + fexp2(v2.x - ym0)
                 + fexp2(v3.x - ym0) + fexp2(v4.x - ym0) + fexp2(v5.x - ym0);
        float s1 = fexp2(v0.y - ym1) + fexp2(v1.y - ym1) + fexp2(v2.y - ym1)
                 + fexp2(v3.y - ym1) + fexp2(v4.y - ym1) + fexp2(v5.y - ym1);
        float gg0 = (ym0 + flog2(s0)) * (-K2 * ga);
        float gg1 = (ym1 + flog2(s1)) * (-K2 * gb);
        o0p[rr] = f2bf(gg0);
        o1p[rr] = f2bf(gg1);
        if (hh < M_DIM) {
            atomicAdd(&sm.mf.shead[0][hh], fexp2(gg0 * C2));
            atomicAdd(&sm.mf.shead[1][hh], fexp2(gg1 * C2));
        }
        mc = mn; ga = gan; gb = gbn;
    }
    __syncthreads();

    // phase 3: val_new columns of out (reconstruct val = -K2*y)
    {
        const int p0 = tid * 2;
        float4 yq = *(const float4*)&sm.mf.vrow2[p0];
        float v00 = -K2 * yq.x, v10 = -K2 * yq.y;   // p0   row0,row1
        float v01 = -K2 * yq.z, v11 = -K2 * yq.w;   // p0+1 row0,row1
        if (tid < M_DIM / 2) {
            float s00 = sm.mf.shead[0][p0], s01 = sm.mf.shead[0][p0 + 1];
            float s10 = sm.mf.shead[1][p0], s11 = sm.mf.shead[1][p0 + 1];
            if (s00 > 0.0f) v00 = fmaxf(v00, K3 * flog2(s00));
            if (s01 > 0.0f) v01 = fmaxf(v01, K3 * flog2(s01));
            if (s10 > 0.0f) v10 = fmaxf(v10, K3 * flog2(s10));
            if (s11 > 0.0f) v11 = fmaxf(v11, K3 * flog2(s11));
        }
        *(float2*)(outp + (size_t)b0 * OUT_STRIDE + p0)       = make_float2(v00, v01);
        *(float2*)(outp + (size_t)(b0 + 1) * OUT_STRIDE + p0) = make_float2(v10, v11);
    }
}

// ---------------------------------------------------------------------------
// global_load_lds 16B staging, XOR-swizzled source, linear LDS dest. BK=128.
// ---------------------------------------------------------------------------
__device__ __forceinline__ void stage16(unsigned short* lds,
                                        const unsigned short* gsrc,
                                        int K, int c)
{
    const int row = c >> 4, slot = c & 15;
    const int k8 = slot ^ (row & 15);      // logical 16B chunk at this slot
    __builtin_amdgcn_global_load_lds(
        (const __attribute__((address_space(1))) void*)(gsrc + (size_t)row * K + k8 * 8),
        (__attribute__((address_space(3))) void*)(lds + c * 8), 16, 0, 0);
}

// ---------------------------------------------------------------------------
// Merged GEMM kernel, 768 blocks x 256 threads:
//   bid < 512 : main  [S|lam_logic] partials: BM=128,BN=64,BK=128, K=4096, z=4
//   bid >= 512: lam_ment partials:            BM=64, BN=64,BK=128, K=256,  z=2
// lam blocks run concurrently in main GEMM's spare wave slots.
// ---------------------------------------------------------------------------
__global__ __launch_bounds__(256) void gemm_all(
    const unsigned short* __restrict__ g_bf,
    const unsigned short* __restrict__ GAT,
    const unsigned short* __restrict__ mclip,
    const unsigned short* __restrict__ w_bf,
    float* __restrict__ mainp, float* __restrict__ lamp)
{
    __shared__ __align__(16) unsigned short Alds[128 * 128];
    __shared__ __align__(16) unsigned short Blds[64 * 128];
    const int bid = blockIdx.x;
    const int tid = threadIdx.x;
    const int lane = tid & 63, wid = tid >> 6;
    const int wr = wid >> 1, wc = wid & 1;

    if (bid < 512) {
        // ---- main path: grid (16 m, 8 n, 4 z) ----
        const int m0 = (bid & 15) * 128;
        const int n0 = ((bid >> 4) & 7) * 64;
        const int z  = bid >> 7;
        const int K = R_DIM, Kc = R_DIM / 4, k0 = z * Kc, NS = 512;
        float* part = mainp + (size_t)z * B_DIM * NS;
        f32x4 acc[4][2] = {};

        for (int kt = 0; kt < Kc; kt += 128) {
            const unsigned short* Ab = g_bf + (size_t)m0 * K + k0 + kt;
            const unsigned short* Bb = GAT  + (size_t)n0 * K + k0 + kt;
            #pragma unroll
            for (int q = 0; q < 8; q++) stage16(Alds, Ab, K, tid + q * 256);
            #pragma unroll
            for (int q = 0; q < 4; q++) stage16(Blds, Bb, K, tid + q * 256);
            __syncthreads();
            #pragma unroll
            for (int ks = 0; ks < 4; ks++) {
                const int k8 = ks * 4 + (lane >> 4);
                const int ra = wr * 64 + (lane & 15);
                const int rb = wc * 32 + (lane & 15);
                const int sa = (k8 ^ (ra & 15)) << 3;
                const int sb = (k8 ^ (rb & 15)) << 3;
                short8 a0 = *(const short8*)&Alds[(ra)      * 128 + sa];
                short8 a1 = *(const short8*)&Alds[(ra + 16) * 128 + sa];
                short8 a2 = *(const short8*)&Alds[(ra + 32) * 128 + sa];
                short8 a3 = *(const short8*)&Alds[(ra + 48) * 128 + sa];
                short8 b0 = *(const short8*)&Blds[(rb)      * 128 + sb];
                short8 b1 = *(const short8*)&Blds[(rb + 16) * 128 + sb];
                acc[0][0] = __builtin_amdgcn_mfma_f32_16x16x32_bf16(a0, b0, acc[0][0], 0, 0, 0);
                acc[0][1] = __builtin_amdgcn_mfma_f32_16x16x32_bf16(a0, b1, acc[0][1], 0, 0, 0);
                acc[1][0] = __builtin_amdgcn_mfma_f32_16x16x32_bf16(a1, b0, acc[1][0], 0, 0, 0);
                acc[1][1] = __builtin_amdgcn_mfma_f32_16x16x32_bf16(a1, b1, acc[1][1], 0, 0, 0);
                acc[2][0] = __builtin_amdgcn_mfma_f32_16x16x32_bf16(a2, b0, acc[2][0], 0, 0, 0);
                acc[2][1] = __builtin_amdgcn_mfma_f32_16x16x32_bf16(a2, b1, acc[2][1], 0, 0, 0);
                acc[3][0] = __builtin_amdgcn_mfma_f32_16x16x32_bf16(a3, b0, acc[3][0], 0, 0, 0);
                acc[3][1] = __builtin_amdgcn_mfma_f32_16x16x32_bf16(a3, b1, acc[3][1], 0, 0, 0);
            }
            __syncthreads();
        }
        const int rbase = (lane >> 4) * 4;
        const int cbase = lane & 15;
        #pragma unroll
        for (int i = 0; i < 4; i++) {
            #pragma unroll
            for (int j = 0; j < 2; j++) {
                const int gn = n0 + wc * 32 + j * 16 + cbase;
                #pragma unroll
                for (int q = 0; q < 4; q++) {
                    const int gm = m0 + wr * 64 + i * 16 + rbase + q;
                    part[(size_t)gm * NS + gn] = acc[i][j][q];
                }
            }
        }
    } else {
        // ---- lam path: grid (32 m, 4 n, 2 z) ----
        const int l = bid - 512;
        const int m0 = (l & 31) * 64;
        const int n0 = ((l >> 5) & 3) * 64;
        const int z  = l >> 7;
        const int K = M_DIM, Kc = M_DIM / 2, k0 = z * Kc, NS = A_DIM;
        float* part = lamp + (size_t)z * B_DIM * NS;
        f32x4 acc[2][2] = {};

        // Kc = 128 -> single K-tile
        const unsigned short* Ab = mclip + (size_t)m0 * K + k0;
        const unsigned short* Bb = w_bf  + (size_t)n0 * K + k0;
        #pragma unroll
        for (int q = 0; q < 4; q++) {
            stage16(Alds, Ab, K, tid + q * 256);
            stage16(Blds, Bb, K, tid + q * 256);
        }
        __syncthreads();
        #pragma unroll
        for (int ks = 0; ks < 4; ks++) {
            const int k8 = ks * 4 + (lane >> 4);
            const int r0a = wr * 32 + (lane & 15);
            const int r0b = wc * 32 + (lane & 15);
            const int sa = (k8 ^ (r0a & 15)) << 3;
            const int sb = (k8 ^ (r0b & 15)) << 3;
            short8 a0 = *(const short8*)&Alds[(r0a)      * 128 + sa];
            short8 a1 = *(const short8*)&Alds[(r0a + 16) * 128 + sa];
            short8 b0 = *(const short8*)&Blds[(r0b)      * 128 + sb];
            short8 b1 = *(const short8*)&Blds[(r0b + 16) * 128 + sb];
            acc[0][0] = __builtin_amdgcn_mfma_f32_16x16x32_bf16(a0, b0, acc[0][0], 0, 0, 0);
            acc[0][1] = __builtin_amdgcn_mfma_f32_16x16x32_bf16(a0, b1, acc[0][1], 0, 0, 0);
            acc[1][0] = __builtin_amdgcn_mfma_f32_16x16x32_bf16(a1, b0, acc[1][0], 0, 0, 0);
            acc[1][1] = __builtin_amdgcn_mfma_f32_16x16x32_bf16(a1, b1, acc[1][1], 0, 0, 0);
        }
        const int rbase = (lane >> 4) * 4;
        const int cbase = lane & 15;
        #pragma unroll
        for (int i = 0; i < 2; i++) {
            #pragma unroll
            for (int j = 0; j < 2; j++) {
                const int gn = n0 + wc * 32 + j * 16 + cbase;
                #pragma unroll
                for (int q = 0; q < 4; q++) {
                    const int gm = m0 + wr * 32 + i * 16 + rbase + q;
                    part[(size_t)gm * NS + gn] = acc[i][j][q];
                }
            }
        }
    }
}

// ---------------------------------------------------------------------------
// Epilogue: sum split-K partials; relu(main); lam cols += softplus(b+lam_ment)
// ---------------------------------------------------------------------------
__global__ __launch_bounds__(256) void epilogue(
    const float* __restrict__ mainpart, const float* __restrict__ lampart,
    const float* __restrict__ bvec, float* __restrict__ outp)
{
    const int idx = blockIdx.x * 256 + threadIdx.x;   // over 2048*128
    const int m = idx >> 7, n4 = idx & 127;
    const size_t mb = (size_t)m * 128 + n4;           // float4 units (NS=512)
    const size_t zs = (size_t)B_DIM * 128;
    float4 s = ((const float4*)mainpart)[mb];
    #pragma unroll
    for (int z = 1; z < 4; z++) {
        float4 t = ((const float4*)mainpart)[mb + z * zs];
        s.x += t.x; s.y += t.y; s.z += t.z; s.w += t.w;
    }
    s.x = fmaxf(s.x, 0.0f); s.y = fmaxf(s.y, 0.0f);
    s.z = fmaxf(s.z, 0.0f); s.w = fmaxf(s.w, 0.0f);
    if (n4 >= 64) {
        const int na = n4 - 64;                       // float4 idx in 256-col lam
        const size_t lb = (size_t)m * 64 + na;
        float4 l0 = ((const float4*)lampart)[lb];
        float4 l1 = ((const float4*)lampart)[lb + (size_t)B_DIM * 64];
        float4 bb = ((const float4*)bvec)[na];
        float x0 = bb.x + l0.x + l1.x, x1 = bb.y + l0.y + l1.y;
        float x2 = bb.z + l0.z + l1.z, x3 = bb.w + l0.w + l1.w;
        s.x += (x0 > 20.0f) ? x0 : log1pf(__expf(x0));
        s.y += (x1 > 20.0f) ? x1 : log1pf(__expf(x1));
        s.z += (x2 > 20.0f) ? x2 : log1pf(__expf(x2));
        s.w += (x3 > 20.0f) ? x3 : log1pf(__expf(x3));
    }
    ((float4*)(outp + (size_t)m * OUT_STRIDE + 2048))[n4] = s;
}

// ---------------------------------------------------------------------------
extern "C" void kernel_launch(void* const* d_in, const int* in_sizes, int n_in,
                              void* d_out, int out_size, void* d_ws, size_t ws_size,
                              hipStream_t stream)
{
    const float* M_minus = (const float*)d_in[0];
    const float* amask   = (const float*)d_in[1];
    const float* gate    = (const float*)d_in[2];
    const float* bmask   = (const float*)d_in[3];
    const float* isM     = (const float*)d_in[4];
    const float* isA     = (const float*)d_in[5];
    const float* GA      = (const float*)d_in[6];
    const float* GB      = (const float*)d_in[7];
    const float* bvec    = (const float*)d_in[8];
    const float* w       = (const float*)d_in[9];
    const int*   bidx    = (const int*)d_in[10];
    const int*   hidx    = (const int*)d_in[11];
    float* outp = (float*)d_out;

    char* ws = (char*)d_ws;
    unsigned short* g_bf   = (unsigned short*)(ws + 0);          // 16 MiB
    unsigned short* GAT    = (unsigned short*)(ws + (16u<<20));  // 2 MiB
    unsigned short* GBT    = (unsigned short*)(ws + (18u<<20));  // 2 MiB (contiguous after GAT)
    unsigned short* w_bf   = (unsigned short*)(ws + (20u<<20));  // 128 KiB
    uint4*          meta   = (uint4*)(ws + (20u<<20) + (256u<<10)); // 64 KiB
    unsigned short* mclip  = (unsigned short*)(ws + (21u<<20));  // 1 MiB
    float*          mainp  = (float*)(ws + (22u<<20));           // 4 x 4 MiB
    float*          lamp   = (float*)(ws + (38u<<20));           // 2 x 2 MiB

    prep_meta<<<dim3(R_DIM / 64), dim3(64), 0, stream>>>(bidx, bmask, hidx, meta);
    main_fused<<<dim3(B_DIM / NB), dim3(1024), 0, stream>>>(
        M_minus, amask, gate, meta, GA, GB, isM, isA, w,
        GAT, GBT, w_bf, g_bf, mclip, outp);
    gemm_all<<<dim3(768), dim3(256), 0, stream>>>(
        g_bf, GAT, mclip, w_bf, mainp, lamp);
    epilogue<<<dim3((B_DIM * 128) / 256), dim3(256), 0, stream>>>(
        mainp, lamp, bvec, outp);
}

// Round 9
// 49.341 us; speedup vs baseline: 1.2601x; 1.0283x over previous
//
#include <hip/hip_runtime.h>

typedef __attribute__((ext_vector_type(8))) short short8;
typedef __attribute__((ext_vector_type(4))) float f32x4;

#define B_DIM 2048
#define P_DIM 2048
#define R_DIM 4096
#define H_DIM 6
#define M_DIM 256
#define A_DIM 256
#define OUT_STRIDE 2560   // P + M + A
#define NB 2              // batch rows per main_fused block

// exp2-form constants: y = -C1*val;  g = -K2*log2(sum exp2(y))*gate
#define C1 14.426950408889634f   // 10/ln2 = 1/(tau*ln2)
#define K2 0.06931471805599453f  // ln2/10
#define C2 7.213475204444817f    // 5/ln2
#define K3 0.13862943611198906f  // ln2/5

static __device__ __forceinline__ float fexp2(float x) { return __builtin_amdgcn_exp2f(x); }
static __device__ __forceinline__ float flog2(float x) { return __builtin_amdgcn_logf(x); }

static __device__ __forceinline__ unsigned short f2bf(float f) {
    unsigned u = __builtin_bit_cast(unsigned, f);
    u += 0x7fffu + ((u >> 16) & 1u);          // round-to-nearest-even
    return (unsigned short)(u >> 16);
}
static __device__ __forceinline__ unsigned short f2h(float f) {
    return __builtin_bit_cast(unsigned short, (_Float16)f);
}
static __device__ __forceinline__ float h2f(unsigned short u) {
    return (float)__builtin_bit_cast(_Float16, u);
}

// ---------------------------------------------------------------------------
// prep_meta: pack rule metadata (6x u16 idx, masked -> sentinel 2048; u16
// head, 0xFFFF if >=256). Must precede main_fused (which consumes meta).
// ---------------------------------------------------------------------------
__global__ __launch_bounds__(64) void prep_meta(
    const int* __restrict__ bidx, const float* __restrict__ bmask,
    const int* __restrict__ hidx, uint4* __restrict__ meta)
{
    const int r = blockIdx.x * 64 + threadIdx.x;   // 4096
    const int* bi = bidx + r * H_DIM;
    const float* bm = bmask + r * H_DIM;
    unsigned s[H_DIM];
    #pragma unroll
    for (int h = 0; h < H_DIM; h++)
        s[h] = (bm[h] > 0.0f) ? (unsigned)bi[h] : 2048u;
    const int hh = hidx[r];
    unsigned sh = (hh < M_DIM) ? (unsigned)hh : 0xFFFFu;
    uint4 m;
    m.x = s[0] | (s[1] << 16);
    m.y = s[2] | (s[3] << 16);
    m.z = s[4] | (s[5] << 16);
    m.w = sh;
    meta[r] = m;
}

// ---------------------------------------------------------------------------
// Main fused kernel: NB=2 rows/block, 1024 threads, grid 1024.
// Prologue (blocks 0..575): 4 prep units each (transpose+scale GA/GB tile,
// or w-cast chunk) using LDS scratch unioned with vrow.
// vrow interleaved float2 {row0,row1}; phase 2 is a DIRECT bounded LSE:
// s = sum exp2(y_h) (y in [-14.43, 0]; masked sentinel underflows to 0).
// ---------------------------------------------------------------------------
__global__ __launch_bounds__(1024, 8) void main_fused(
    const float* __restrict__ M_minus, const float* __restrict__ amask,
    const float* __restrict__ gate,    const uint4* __restrict__ meta,
    const float* __restrict__ GA, const float* __restrict__ GB,
    const float* __restrict__ isM, const float* __restrict__ isA,
    const float* __restrict__ w,
    unsigned short* __restrict__ GAT, unsigned short* __restrict__ GBT,
    unsigned short* __restrict__ wb,
    unsigned short* __restrict__ g_bf, unsigned short* __restrict__ mclip_bf,
    float* __restrict__ outp)
{
    __shared__ __align__(16) union SM {
        struct {
            float2 vrow2[2052];          // [p] = {y(row0,p), y(row1,p)}
            float shead[NB][M_DIM];
        } mf;
        float prep[4][32][33];
    } sm;
    const int bid = blockIdx.x;
    const int tid = threadIdx.x;
    const int b0 = bid * NB;

    // ---- fused prep: 576 blocks x 4 units (2048 transpose + 256 w-cast) ----
    if (bid < 576) {
        const int s = tid >> 8, lt = tid & 255;
        const int u = bid * 4 + s;
        if (u < 2048) {
            const int which = u >> 10;
            const int rem = u & 1023;
            const float* src = which ? GB : GA;
            const float* scv = which ? isA : isM;
            const int r0 = (rem >> 3) * 32;   // K (=R) dim
            const int n0 = (rem & 7) * 32;    // N (=256) dim
            const int tx = lt & 31, ty = lt >> 5;
            #pragma unroll
            for (int q = 0; q < 4; q++) {
                int rr = ty + q * 8;
                sm.prep[s][rr][tx] = scv[r0 + rr] * src[(size_t)(r0 + rr) * 256 + n0 + tx];
            }
        } else {
            const int i = (u - 2048) * 256 + lt;   // 65536
            wb[i] = f2bf(w[i]);
        }
        __syncthreads();
        if (u < 2048) {
            const int which = u >> 10;
            const int rem = u & 1023;
            unsigned short* dst = which ? GBT : GAT;
            const int r0 = (rem >> 3) * 32;
            const int n0 = (rem & 7) * 32;
            const int tx = lt & 31, ty = lt >> 5;
            #pragma unroll
            for (int q = 0; q < 4; q++) {
                int nn = ty + q * 8;
                dst[(size_t)(n0 + nn) * R_DIM + r0 + tx] = f2bf(sm.prep[s][tx][nn]);
            }
        }
        __syncthreads();   // protect LDS reuse by mf phases
    }

    // ---- mf init ----
    if (tid < NB * M_DIM) sm.mf.shead[tid >> 8][tid & 255] = 0.0f;
    if (tid == 0) sm.mf.vrow2[2048] = make_float2(-1.0e9f, -1.0e9f);  // sentinel

    // phase 1: each thread builds p0=2t, p0+1 for both rows (interleaved)
    {
        const int p0 = tid * 2;
        float2 a0 = *(const float2*)(amask + (size_t)b0 * P_DIM + p0);
        float2 a1 = *(const float2*)(amask + (size_t)(b0 + 1) * P_DIM + p0);
        if (tid < M_DIM / 2) {
            float2 m0 = *(const float2*)(M_minus + (size_t)b0 * M_DIM + p0);
            float2 m1 = *(const float2*)(M_minus + (size_t)(b0 + 1) * M_DIM + p0);
            float mc00 = fminf(fmaxf(m0.x, 0.0f), 1.0f);
            float mc01 = fminf(fmaxf(m0.y, 0.0f), 1.0f);
            float mc10 = fminf(fmaxf(m1.x, 0.0f), 1.0f);
            float mc11 = fminf(fmaxf(m1.y, 0.0f), 1.0f);
            ushort2 w0; w0.x = f2bf(mc00); w0.y = f2bf(mc01);
            ushort2 w1; w1.x = f2bf(mc10); w1.y = f2bf(mc11);
            *(ushort2*)(mclip_bf + (size_t)b0 * M_DIM + p0) = w0;
            *(ushort2*)(mclip_bf + (size_t)(b0 + 1) * M_DIM + p0) = w1;
            a0.x = fmaxf(mc00, a0.x); a0.y = fmaxf(mc01, a0.y);
            a1.x = fmaxf(mc10, a1.x); a1.y = fmaxf(mc11, a1.y);
        }
        float4 yq;
        yq.x = -C1 * a0.x; yq.y = -C1 * a1.x;   // p0:   (row0, row1)
        yq.z = -C1 * a0.y; yq.w = -C1 * a1.y;   // p0+1: (row0, row1)
        *(float4*)&sm.mf.vrow2[p0] = yq;
    }
    __syncthreads();

    // phase 2: rules, 4 iterations, prefetch distance 1, 6 x b64 gathers,
    // direct LSE (no max subtraction needed: y bounded in [-14.43, 0])
    const float* g0p = gate + (size_t)b0 * R_DIM;
    const float* g1p = gate + (size_t)(b0 + 1) * R_DIM;
    unsigned short* o0p = g_bf + (size_t)b0 * R_DIM;
    unsigned short* o1p = g_bf + (size_t)(b0 + 1) * R_DIM;

    uint4 mc = meta[tid];
    float ga = g0p[tid], gb = g1p[tid];
    #pragma unroll
    for (int it = 0; it < R_DIM / 1024; it++) {
        const int rr = tid + it * 1024;
        uint4 mn = mc; float gan = ga, gbn = gb;
        if (it < R_DIM / 1024 - 1) {
            mn  = meta[rr + 1024];
            gan = g0p[rr + 1024];
            gbn = g1p[rr + 1024];
        }
        const int i0 = mc.x & 0xFFFF, i1 = mc.x >> 16;
        const int i2 = mc.y & 0xFFFF, i3 = mc.y >> 16;
        const int i4 = mc.z & 0xFFFF, i5 = mc.z >> 16;
        const int hh = mc.w & 0xFFFF;
        float2 v0 = sm.mf.vrow2[i0], v1 = sm.mf.vrow2[i1], v2 = sm.mf.vrow2[i2];
        float2 v3 = sm.mf.vrow2[i3], v4 = sm.mf.vrow2[i4], v5 = sm.mf.vrow2[i5];

        float s0 = fexp2(v0.x) + fexp2(v1.x) + fexp2(v2.x)
                 + fexp2(v3.x) + fexp2(v4.x) + fexp2(v5.x);
        float s1 = fexp2(v0.y) + fexp2(v1.y) + fexp2(v2.y)
                 + fexp2(v3.y) + fexp2(v4.y) + fexp2(v5.y);
        float gg0 = flog2(s0) * (-K2 * ga);
        float gg1 = flog2(s1) * (-K2 * gb);
        o0p[rr] = f2bf(gg0);
        o1p[rr] = f2bf(gg1);
        if (hh < M_DIM) {
            atomicAdd(&sm.mf.shead[0][hh], fexp2(gg0 * C2));
            atomicAdd(&sm.mf.shead[1][hh], fexp2(gg1 * C2));
        }
        mc = mn; ga = gan; gb = gbn;
    }
    __syncthreads();

    // phase 3: val_new columns of out (reconstruct val = -K2*y)
    {
        const int p0 = tid * 2;
        float4 yq = *(const float4*)&sm.mf.vrow2[p0];
        float v00 = -K2 * yq.x, v10 = -K2 * yq.y;   // p0   row0,row1
        float v01 = -K2 * yq.z, v11 = -K2 * yq.w;   // p0+1 row0,row1
        if (tid < M_DIM / 2) {
            float s00 = sm.mf.shead[0][p0], s01 = sm.mf.shead[0][p0 + 1];
            float s10 = sm.mf.shead[1][p0], s11 = sm.mf.shead[1][p0 + 1];
            if (s00 > 0.0f) v00 = fmaxf(v00, K3 * flog2(s00));
            if (s01 > 0.0f) v01 = fmaxf(v01, K3 * flog2(s01));
            if (s10 > 0.0f) v10 = fmaxf(v10, K3 * flog2(s10));
            if (s11 > 0.0f) v11 = fmaxf(v11, K3 * flog2(s11));
        }
        *(float2*)(outp + (size_t)b0 * OUT_STRIDE + p0)       = make_float2(v00, v01);
        *(float2*)(outp + (size_t)(b0 + 1) * OUT_STRIDE + p0) = make_float2(v10, v11);
    }
}

// ---------------------------------------------------------------------------
// global_load_lds 16B staging, XOR-swizzled source, linear LDS dest. BK=128.
// ---------------------------------------------------------------------------
__device__ __forceinline__ void stage16(unsigned short* lds,
                                        const unsigned short* gsrc,
                                        int K, int c)
{
    const int row = c >> 4, slot = c & 15;
    const int k8 = slot ^ (row & 15);      // logical 16B chunk at this slot
    __builtin_amdgcn_global_load_lds(
        (const __attribute__((address_space(1))) void*)(gsrc + (size_t)row * K + k8 * 8),
        (__attribute__((address_space(3))) void*)(lds + c * 8), 16, 0, 0);
}

// ---------------------------------------------------------------------------
// Merged GEMM kernel, 768 blocks x 256 threads, f16 partials:
//   bid < 512 : main [S|lam_logic]: BM=128,BN=64,BK=128, K=4096, z=4.
//               XCD-chunk swizzle: logical = (bid&7)*64 + bid>>3 so each XCD
//               (phys bid%8) owns all-m x 4-n x 1-z -> A-slice L2 reuse.
//   bid >= 512: lam_ment: BM=64,BN=64,BK=128, K=256, z=2.
// ---------------------------------------------------------------------------
__global__ __launch_bounds__(256) void gemm_all(
    const unsigned short* __restrict__ g_bf,
    const unsigned short* __restrict__ GAT,
    const unsigned short* __restrict__ mclip,
    const unsigned short* __restrict__ w_bf,
    unsigned short* __restrict__ mainp, unsigned short* __restrict__ lamp)
{
    __shared__ __align__(16) unsigned short Alds[128 * 128];
    __shared__ __align__(16) unsigned short Blds[64 * 128];
    const int bid = blockIdx.x;
    const int tid = threadIdx.x;
    const int lane = tid & 63, wid = tid >> 6;
    const int wr = wid >> 1, wc = wid & 1;

    if (bid < 512) {
        // ---- main path: logical (16 m, 8 n, 4 z), XCD-chunk swizzled ----
        const int l = (bid & 7) * 64 + (bid >> 3);
        const int m0 = (l & 15) * 128;
        const int n0 = ((l >> 4) & 7) * 64;
        const int z  = l >> 7;
        const int K = R_DIM, Kc = R_DIM / 4, k0 = z * Kc, NS = 512;
        unsigned short* part = mainp + (size_t)z * B_DIM * NS;
        f32x4 acc[4][2] = {};

        for (int kt = 0; kt < Kc; kt += 128) {
            const unsigned short* Ab = g_bf + (size_t)m0 * K + k0 + kt;
            const unsigned short* Bb = GAT  + (size_t)n0 * K + k0 + kt;
            #pragma unroll
            for (int q = 0; q < 8; q++) stage16(Alds, Ab, K, tid + q * 256);
            #pragma unroll
            for (int q = 0; q < 4; q++) stage16(Blds, Bb, K, tid + q * 256);
            __syncthreads();
            #pragma unroll
            for (int ks = 0; ks < 4; ks++) {
                const int k8 = ks * 4 + (lane >> 4);
                const int ra = wr * 64 + (lane & 15);
                const int rb = wc * 32 + (lane & 15);
                const int sa = (k8 ^ (ra & 15)) << 3;
                const int sb = (k8 ^ (rb & 15)) << 3;
                short8 a0 = *(const short8*)&Alds[(ra)      * 128 + sa];
                short8 a1 = *(const short8*)&Alds[(ra + 16) * 128 + sa];
                short8 a2 = *(const short8*)&Alds[(ra + 32) * 128 + sa];
                short8 a3 = *(const short8*)&Alds[(ra + 48) * 128 + sa];
                short8 b0 = *(const short8*)&Blds[(rb)      * 128 + sb];
                short8 b1 = *(const short8*)&Blds[(rb + 16) * 128 + sb];
                acc[0][0] = __builtin_amdgcn_mfma_f32_16x16x32_bf16(a0, b0, acc[0][0], 0, 0, 0);
                acc[0][1] = __builtin_amdgcn_mfma_f32_16x16x32_bf16(a0, b1, acc[0][1], 0, 0, 0);
                acc[1][0] = __builtin_amdgcn_mfma_f32_16x16x32_bf16(a1, b0, acc[1][0], 0, 0, 0);
                acc[1][1] = __builtin_amdgcn_mfma_f32_16x16x32_bf16(a1, b1, acc[1][1], 0, 0, 0);
                acc[2][0] = __builtin_amdgcn_mfma_f32_16x16x32_bf16(a2, b0, acc[2][0], 0, 0, 0);
                acc[2][1] = __builtin_amdgcn_mfma_f32_16x16x32_bf16(a2, b1, acc[2][1], 0, 0, 0);
                acc[3][0] = __builtin_amdgcn_mfma_f32_16x16x32_bf16(a3, b0, acc[3][0], 0, 0, 0);
                acc[3][1] = __builtin_amdgcn_mfma_f32_16x16x32_bf16(a3, b1, acc[3][1], 0, 0, 0);
            }
            __syncthreads();
        }
        const int rbase = (lane >> 4) * 4;
        const int cbase = lane & 15;
        #pragma unroll
        for (int i = 0; i < 4; i++) {
            #pragma unroll
            for (int j = 0; j < 2; j++) {
                const int gn = n0 + wc * 32 + j * 16 + cbase;
                #pragma unroll
                for (int q = 0; q < 4; q++) {
                    const int gm = m0 + wr * 64 + i * 16 + rbase + q;
                    part[(size_t)gm * NS + gn] = f2h(acc[i][j][q]);
                }
            }
        }
    } else {
        // ---- lam path: grid (32 m, 4 n, 2 z) ----
        const int l = bid - 512;
        const int m0 = (l & 31) * 64;
        const int n0 = ((l >> 5) & 3) * 64;
        const int z  = l >> 7;
        const int K = M_DIM, Kc = M_DIM / 2, k0 = z * Kc, NS = A_DIM;
        unsigned short* part = lamp + (size_t)z * B_DIM * NS;
        f32x4 acc[2][2] = {};

        // Kc = 128 -> single K-tile
        const unsigned short* Ab = mclip + (size_t)m0 * K + k0;
        const unsigned short* Bb = w_bf  + (size_t)n0 * K + k0;
        #pragma unroll
        for (int q = 0; q < 4; q++) {
            stage16(Alds, Ab, K, tid + q * 256);
            stage16(Blds, Bb, K, tid + q * 256);
        }
        __syncthreads();
        #pragma unroll
        for (int ks = 0; ks < 4; ks++) {
            const int k8 = ks * 4 + (lane >> 4);
            const int r0a = wr * 32 + (lane & 15);
            const int r0b = wc * 32 + (lane & 15);
            const int sa = (k8 ^ (r0a & 15)) << 3;
            const int sb = (k8 ^ (r0b & 15)) << 3;
            short8 a0 = *(const short8*)&Alds[(r0a)      * 128 + sa];
            short8 a1 = *(const short8*)&Alds[(r0a + 16) * 128 + sa];
            short8 b0 = *(const short8*)&Blds[(r0b)      * 128 + sb];
            short8 b1 = *(const short8*)&Blds[(r0b + 16) * 128 + sb];
            acc[0][0] = __builtin_amdgcn_mfma_f32_16x16x32_bf16(a0, b0, acc[0][0], 0, 0, 0);
            acc[0][1] = __builtin_amdgcn_mfma_f32_16x16x32_bf16(a0, b1, acc[0][1], 0, 0, 0);
            acc[1][0] = __builtin_amdgcn_mfma_f32_16x16x32_bf16(a1, b0, acc[1][0], 0, 0, 0);
            acc[1][1] = __builtin_amdgcn_mfma_f32_16x16x32_bf16(a1, b1, acc[1][1], 0, 0, 0);
        }
        const int rbase = (lane >> 4) * 4;
        const int cbase = lane & 15;
        #pragma unroll
        for (int i = 0; i < 2; i++) {
            #pragma unroll
            for (int j = 0; j < 2; j++) {
                const int gn = n0 + wc * 32 + j * 16 + cbase;
                #pragma unroll
                for (int q = 0; q < 4; q++) {
                    const int gm = m0 + wr * 32 + i * 16 + rbase + q;
                    part[(size_t)gm * NS + gn] = f2h(acc[i][j][q]);
                }
            }
        }
    }
}

// ---------------------------------------------------------------------------
// Epilogue: sum f16 split-K partials; relu(main); lam cols +=
// softplus(b + lam_ment). float4-out over 2048x512.
// ---------------------------------------------------------------------------
__global__ __launch_bounds__(256) void epilogue(
    const unsigned short* __restrict__ mainpart,
    const unsigned short* __restrict__ lampart,
    const float* __restrict__ bvec, float* __restrict__ outp)
{
    const int idx = blockIdx.x * 256 + threadIdx.x;   // over 2048*128
    const int m = idx >> 7, n4 = idx & 127;
    const size_t mb = (size_t)m * 128 + n4;           // ushort4 units (NS=512)
    const size_t zs = (size_t)B_DIM * 128;
    float sx = 0.0f, sy = 0.0f, sz = 0.0f, sw = 0.0f;
    #pragma unroll
    for (int z = 0; z < 4; z++) {
        ushort4 t = ((const ushort4*)mainpart)[mb + z * zs];
        sx += h2f(t.x); sy += h2f(t.y); sz += h2f(t.z); sw += h2f(t.w);
    }
    sx = fmaxf(sx, 0.0f); sy = fmaxf(sy, 0.0f);
    sz = fmaxf(sz, 0.0f); sw = fmaxf(sw, 0.0f);
    if (n4 >= 64) {
        const int na = n4 - 64;                       // ushort4 idx in 256-col lam
        const size_t lb = (size_t)m * 64 + na;
        const size_t ls = (size_t)B_DIM * 64;
        ushort4 u0 = ((const ushort4*)lampart)[lb];
        ushort4 u1 = ((const ushort4*)lampart)[lb + ls];
        float4 bb = ((const float4*)bvec)[na];
        float x0 = bb.x + h2f(u0.x) + h2f(u1.x);
        float x1 = bb.y + h2f(u0.y) + h2f(u1.y);
        float x2 = bb.z + h2f(u0.z) + h2f(u1.z);
        float x3 = bb.w + h2f(u0.w) + h2f(u1.w);
        sx += (x0 > 20.0f) ? x0 : log1pf(__expf(x0));
        sy += (x1 > 20.0f) ? x1 : log1pf(__expf(x1));
        sz += (x2 > 20.0f) ? x2 : log1pf(__expf(x2));
        sw += (x3 > 20.0f) ? x3 : log1pf(__expf(x3));
    }
    float4 s; s.x = sx; s.y = sy; s.z = sz; s.w = sw;
    ((float4*)(outp + (size_t)m * OUT_STRIDE + 2048))[n4] = s;
}

// ---------------------------------------------------------------------------
extern "C" void kernel_launch(void* const* d_in, const int* in_sizes, int n_in,
                              void* d_out, int out_size, void* d_ws, size_t ws_size,
                              hipStream_t stream)
{
    const float* M_minus = (const float*)d_in[0];
    const float* amask   = (const float*)d_in[1];
    const float* gate    = (const float*)d_in[2];
    const float* bmask   = (const float*)d_in[3];
    const float* isM     = (const float*)d_in[4];
    const float* isA     = (const float*)d_in[5];
    const float* GA      = (const float*)d_in[6];
    const float* GB      = (const float*)d_in[7];
    const float* bvec    = (const float*)d_in[8];
    const float* w       = (const float*)d_in[9];
    const int*   bidx    = (const int*)d_in[10];
    const int*   hidx    = (const int*)d_in[11];
    float* outp = (float*)d_out;

    char* ws = (char*)d_ws;
    unsigned short* g_bf   = (unsigned short*)(ws + 0);          // 16 MiB
    unsigned short* GAT    = (unsigned short*)(ws + (16u<<20));  // 2 MiB
    unsigned short* GBT    = (unsigned short*)(ws + (18u<<20));  // 2 MiB (contiguous after GAT)
    unsigned short* w_bf   = (unsigned short*)(ws + (20u<<20));  // 128 KiB
    uint4*          meta   = (uint4*)(ws + (20u<<20) + (256u<<10)); // 64 KiB
    unsigned short* mclip  = (unsigned short*)(ws + (21u<<20));  // 1 MiB
    unsigned short* mainp  = (unsigned short*)(ws + (22u<<20));  // 4 x 2 MiB (f16)
    unsigned short* lamp   = (unsigned short*)(ws + (38u<<20));  // 2 x 1 MiB (f16)

    prep_meta<<<dim3(R_DIM / 64), dim3(64), 0, stream>>>(bidx, bmask, hidx, meta);
    main_fused<<<dim3(B_DIM / NB), dim3(1024), 0, stream>>>(
        M_minus, amask, gate, meta, GA, GB, isM, isA, w,
        GAT, GBT, w_bf, g_bf, mclip, outp);
    gemm_all<<<dim3(768), dim3(256), 0, stream>>>(
        g_bf, GAT, mclip, w_bf, mainp, lamp);
    epilogue<<<dim3((B_DIM * 128) / 256), dim3(256), 0, stream>>>(
        mainp, lamp, bvec, outp);
}